// Round 15
// baseline (147.617 us; speedup 1.0000x reference)
//
#include <hip/hip_runtime.h>
#include <hip/hip_fp16.h>

#define D 64
#define EPS 1e-12f
#define NPB 512         // nodes per dst-bin
#define NPB_SHIFT 9
#define NB 256          // bin table size (nbins = 196 <= 256)
#define CAP 8192        // per-bin esrc region; bin mean 6144, sd 78 -> 26-sigma
#define CAP_SHIFT 13
#define EPB 4096        // edges per scatter block (chunk written contiguously)
#define FRAG_MAX 512    // max scatter blocks (E <= 2.1M); E=1.2M -> 293
#define SRC_BITS 17     // N = 100000 < 2^17

typedef _Float16 hv2 __attribute__((ext_vector_type(2)));

__device__ inline unsigned bc_u(__half2 h) { return __builtin_bit_cast(unsigned, h); }
__device__ inline __half2  bc_h(unsigned u) { return __builtin_bit_cast(__half2, u); }

__device__ inline float fdot2f(unsigned a, unsigned b, float c) {
#if defined(__has_builtin) && __has_builtin(__builtin_amdgcn_fdot2)
    return __builtin_amdgcn_fdot2(__builtin_bit_cast(hv2, a),
                                  __builtin_bit_cast(hv2, b), c, false);
#else
    __half2 ah = bc_h(a), bh = bc_h(b);
    return c + __low2float(ah) * __low2float(bh)
             + __high2float(ah) * __high2float(bh);
#endif
}

// ---- k1: LDS counting-sort by bin; sorted chunk written CONTIGUOUSLY at
//      pairs[blk*EPB] (private, coalesced); per-bin offsets -> offs_g[blk][.].
//      No global atomics, no memset needed. ----
__global__ __launch_bounds__(1024) void scatter_kernel(
        const int* __restrict__ src,
        const int* __restrict__ dst,
        int* __restrict__ offs_g,         // [nblk][NB+1]
        unsigned* __restrict__ pairs, int E) {
    __shared__ int hist[NB], offs[NB + 1], cursor[NB];
    __shared__ int wsum[4];
    __shared__ int dstbuf[EPB];            // 16 KB
    __shared__ unsigned buf[EPB];          // 16 KB

    int tid  = threadIdx.x;
    int base = blockIdx.x * EPB;
    int cnt  = min(EPB, E - base);

    if (tid < NB) hist[tid] = 0;
    __syncthreads();
    for (int i = tid; i < cnt; i += 1024) {
        int dd = dst[base + i];
        dstbuf[i] = dd;
        atomicAdd(&hist[dd >> NPB_SHIFT], 1);
    }
    __syncthreads();
    // exclusive scan of hist[0..NB): 4 waves, shfl scan + wave sums
    int lane = tid & 63, w = tid >> 6;
    int v = 0, x = 0;
    if (tid < NB) { v = hist[tid]; x = v; }
    #pragma unroll
    for (int off = 1; off < 64; off <<= 1) {
        int t = __shfl_up(x, off, 64);
        if (lane >= off) x += t;
    }
    if (tid < NB && lane == 63) wsum[w] = x;
    __syncthreads();
    if (tid < NB) {
        int add = 0;
        #pragma unroll
        for (int ww = 0; ww < 4; ww++) add += (ww < w) ? wsum[ww] : 0;
        int excl = x + add - v;
        offs[tid] = excl; cursor[tid] = excl;
    }
    if (tid == 0) offs[NB] = cnt;
    __syncthreads();
    // sort into LDS (record: local_dst<<17 | src)
    for (int i = tid; i < cnt; i += 1024) {
        int s = src[base + i], dd = dstbuf[i];
        int b = dd >> NPB_SHIFT;
        int l = atomicAdd(&cursor[b], 1);
        buf[l] = ((unsigned)(dd & (NPB - 1)) << SRC_BITS) | (unsigned)s;
    }
    __syncthreads();
    // contiguous coalesced dump of the sorted chunk
    for (int i = tid; i < cnt; i += 1024)
        pairs[base + i] = buf[i];
    // publish per-bin offsets (entire offs_g row written -> poison-safe)
    for (int i = tid; i <= NB; i += 1024)
        offs_g[blockIdx.x * (NB + 1) + i] = offs[i];
}

// ---- k2 (fused, disjoint block ranges):
//      blocks [0,nbins): csr — gather bin fragments from all chunks into LDS,
//                        then hist+scan+rank scatter -> esrc, rowbeg/rowend
//      blocks [nbins,..): nh — norms + f16 normalized rows ----
__global__ __launch_bounds__(1024) void csr_nh_kernel(
        const unsigned* __restrict__ pairs,
        const int* __restrict__ offs_g,
        int* __restrict__ rowbeg,
        int* __restrict__ rowend,
        int* __restrict__ esrc,
        const float4* __restrict__ feat4,
        float* __restrict__ norms,
        uint2* __restrict__ nh2,
        int N, int nbins, int nblk) {
    __shared__ unsigned buf[CAP];                       // 32 KB
    __shared__ int fragsrc[FRAG_MAX], fraglen[FRAG_MAX], fragdst[FRAG_MAX];
    __shared__ int hist[NPB], offsL[NPB];
    __shared__ int wsum[8];
    __shared__ int totcnt;

    if ((int)blockIdx.x >= nbins) {
        // ---------- nh / norms (f16) ----------
        int gid = (blockIdx.x - nbins) * 1024 + threadIdx.x;
        int row = gid >> 4;
        int lg  = gid & 15;
        if (row >= N) return;
        float4 v = feat4[row * 16 + lg];
        float ss = v.x * v.x + v.y * v.y + v.z * v.z + v.w * v.w;
        #pragma unroll
        for (int off = 1; off < 16; off <<= 1) ss += __shfl_xor(ss, off, 64);
        float nrm = fmaxf(sqrtf(ss), EPS);
        float inv = 1.0f / nrm;
        if (lg == 0) norms[row] = nrm;
        uint2 p;
        p.x = bc_u(__floats2half2_rn(v.x * inv, v.y * inv));
        p.y = bc_u(__floats2half2_rn(v.z * inv, v.w * inv));
        nh2[row * 16 + lg] = p;
        return;
    }

    // ---------- csr ----------
    int b    = blockIdx.x;
    int tid  = threadIdx.x;
    int lane = tid & 63, w = tid >> 6;
    int base = b << CAP_SHIFT;         // esrc region for this bin
    int node0 = b << NPB_SHIFT;

    // fragment lengths for bin b across all scatter chunks
    for (int f = tid; f < nblk; f += 1024) {
        int o0 = offs_g[f * (NB + 1) + b];
        int o1 = offs_g[f * (NB + 1) + b + 1];
        fragsrc[f] = o0;
        fraglen[f] = o1 - o0;
    }
    __syncthreads();
    // wave 0: carry-scan of fragment lengths -> fragdst
    if (tid < 64) {
        int carry = 0;
        for (int c = 0; c < nblk; c += 64) {
            int idx = c + tid;
            int ld = (idx < nblk) ? fraglen[idx] : 0;
            int x = ld;
            #pragma unroll
            for (int off = 1; off < 64; off <<= 1) {
                int t = __shfl_up(x, off, 64);
                if (tid >= off) x += t;
            }
            if (idx < nblk) fragdst[idx] = carry + x - ld;
            carry += __shfl(x, 63, 64);
        }
        if (tid == 0) totcnt = carry;
    }
    if (tid < NPB) hist[tid] = 0;
    __syncthreads();
    // gather-copy fragments into contiguous LDS buf (16 waves round-robin)
    for (int f = w; f < nblk; f += 16) {
        int len = fraglen[f];
        int sb = f * EPB + fragsrc[f];
        int db = fragdst[f];
        for (int j = lane; j < len; j += 64)
            buf[db + j] = pairs[sb + j];
    }
    __syncthreads();
    int cnt = totcnt;
    // rank edges per node (register-staged, 8 per thread)
    unsigned rec[8];
    int      meta[8];     // (local_node<<16) | rank
    #pragma unroll
    for (int k = 0; k < 8; k++) {
        int i = tid + (k << 10);
        if (i < cnt) {
            unsigned p = buf[i];
            int ln  = (int)(p >> SRC_BITS);
            rec[k]  = p & ((1u << SRC_BITS) - 1);
            meta[k] = (ln << 16) | atomicAdd(&hist[ln], 1);
        } else meta[k] = -1;
    }
    __syncthreads();
    // exclusive scan of hist[0..NPB): 8 waves, shfl scan + wave sums
    int v = 0, x = 0;
    if (tid < NPB) { v = hist[tid]; x = v; }
    #pragma unroll
    for (int off = 1; off < 64; off <<= 1) {
        int t = __shfl_up(x, off, 64);
        if (lane >= off) x += t;
    }
    if (tid < NPB && lane == 63) wsum[w] = x;
    __syncthreads();
    if (tid < NPB) {
        int add = 0;
        #pragma unroll
        for (int ww = 0; ww < 8; ww++) add += (ww < w) ? wsum[ww] : 0;
        int excl = x + add - v;
        offsL[tid] = excl;
        int node = node0 + tid;
        if (node < N) { rowbeg[node] = base + excl; rowend[node] = base + excl + v; }
    }
    __syncthreads();
    #pragma unroll
    for (int k = 0; k < 8; k++)
        if (meta[k] >= 0)
            esrc[base + offsL[meta[k] >> 16] + (meta[k] & 0xffff)] = (int)rec[k];
}

// ---- k3: gather — one node per 8-lane group, 4-edge unroll (unchanged) ----
__global__ __launch_bounds__(256) void gather_kernel(const uint4* __restrict__ nh4,
                                                     const float* __restrict__ norms,
                                                     const float* __restrict__ beta_p,
                                                     const int* __restrict__ rowbeg,
                                                     const int* __restrict__ rowend,
                                                     const int* __restrict__ esrc,
                                                     float4* __restrict__ out4, int N) {
    int t    = blockIdx.x * 256 + threadIdx.x;
    int lane = threadIdx.x & 63;
    int g    = lane >> 3;
    int lg   = lane & 7;
    int d    = (t >> 6) * 8 + g;
    if (d >= N) return;

    int j   = rowbeg[d];
    int end = rowend[d];
    float beta = beta_p[0];

    uint4 fdp = nh4[(size_t)d * 8 + lg];

    __half2 acc0 = __float2half2_rn(0.f), acc1 = acc0, acc2 = acc0, acc3 = acc0;
    float ps = 0.f;

    for (; j < end; j += 4) {
        bool v1 = (j + 1 < end), v2 = (j + 2 < end), v3 = (j + 3 < end);
        int s0 = esrc[j];
        int s1 = v1 ? esrc[j + 1] : s0;
        int s2 = v2 ? esrc[j + 2] : s0;
        int s3 = v3 ? esrc[j + 3] : s0;
        uint4 p0 = nh4[(size_t)s0 * 8 + lg];
        uint4 p1 = nh4[(size_t)s1 * 8 + lg];
        uint4 p2 = nh4[(size_t)s2 * 8 + lg];
        uint4 p3 = nh4[(size_t)s3 * 8 + lg];
        float n0 = norms[s0], n1 = norms[s1], n2 = norms[s2], n3 = norms[s3];
        float d0 = fdot2f(p0.x, fdp.x, 0.f), d1 = fdot2f(p1.x, fdp.x, 0.f);
        float d2 = fdot2f(p2.x, fdp.x, 0.f), d3 = fdot2f(p3.x, fdp.x, 0.f);
        d0 = fdot2f(p0.y, fdp.y, d0); d1 = fdot2f(p1.y, fdp.y, d1);
        d2 = fdot2f(p2.y, fdp.y, d2); d3 = fdot2f(p3.y, fdp.y, d3);
        d0 = fdot2f(p0.z, fdp.z, d0); d1 = fdot2f(p1.z, fdp.z, d1);
        d2 = fdot2f(p2.z, fdp.z, d2); d3 = fdot2f(p3.z, fdp.z, d3);
        d0 = fdot2f(p0.w, fdp.w, d0); d1 = fdot2f(p1.w, fdp.w, d1);
        d2 = fdot2f(p2.w, fdp.w, d2); d3 = fdot2f(p3.w, fdp.w, d3);
        #pragma unroll
        for (int off = 1; off < 8; off <<= 1) {
            d0 += __shfl_xor(d0, off, 64);
            d1 += __shfl_xor(d1, off, 64);
            d2 += __shfl_xor(d2, off, 64);
            d3 += __shfl_xor(d3, off, 64);
        }
        float w0 = __expf(beta * d0);
        float w1 = v1 ? __expf(beta * d1) : 0.f;
        float w2 = v2 ? __expf(beta * d2) : 0.f;
        float w3 = v3 ? __expf(beta * d3) : 0.f;
        __half2 q0 = __float2half2_rn(w0 * n0);
        __half2 q1 = __float2half2_rn(w1 * n1);
        __half2 q2 = __float2half2_rn(w2 * n2);
        __half2 q3 = __float2half2_rn(w3 * n3);
        acc0 = __hfma2(q0, bc_h(p0.x), acc0); acc0 = __hfma2(q1, bc_h(p1.x), acc0);
        acc0 = __hfma2(q2, bc_h(p2.x), acc0); acc0 = __hfma2(q3, bc_h(p3.x), acc0);
        acc1 = __hfma2(q0, bc_h(p0.y), acc1); acc1 = __hfma2(q1, bc_h(p1.y), acc1);
        acc1 = __hfma2(q2, bc_h(p2.y), acc1); acc1 = __hfma2(q3, bc_h(p3.y), acc1);
        acc2 = __hfma2(q0, bc_h(p0.z), acc2); acc2 = __hfma2(q1, bc_h(p1.z), acc2);
        acc2 = __hfma2(q2, bc_h(p2.z), acc2); acc2 = __hfma2(q3, bc_h(p3.z), acc2);
        acc3 = __hfma2(q0, bc_h(p0.w), acc3); acc3 = __hfma2(q1, bc_h(p1.w), acc3);
        acc3 = __hfma2(q2, bc_h(p2.w), acc3); acc3 = __hfma2(q3, bc_h(p3.w), acc3);
        ps += w0 + w1 + w2 + w3;
    }

    float r = 1.0f / fmaxf(ps, EPS);
    float4 o0 = {__low2float(acc0) * r, __high2float(acc0) * r,
                 __low2float(acc1) * r, __high2float(acc1) * r};
    float4 o1 = {__low2float(acc2) * r, __high2float(acc2) * r,
                 __low2float(acc3) * r, __high2float(acc3) * r};
    out4[(size_t)d * 16 + lg * 2]     = o0;
    out4[(size_t)d * 16 + lg * 2 + 1] = o1;
}

extern "C" void kernel_launch(void* const* d_in, const int* in_sizes, int n_in,
                              void* d_out, int out_size, void* d_ws, size_t ws_size,
                              hipStream_t stream) {
    const float* feat = (const float*)d_in[0];
    const float* beta = (const float*)d_in[1];
    const int*   src  = (const int*)d_in[2];
    const int*   dst  = (const int*)d_in[3];

    int N = in_sizes[0] / D;
    int E = in_sizes[2];
    int nbins = (N + NPB - 1) / NPB;   // 196 (must be <= NB)
    int nblk  = (E + EPB - 1) / EPB;   // 293 (must be <= FRAG_MAX)

    // ws: pairs[nblk*EPB] u32 | esrc[nbins*CAP] | offs_g[nblk*(NB+1)] |
    //     nh[N*64] f16 | norms[N] | rowbeg[N] | rowend[N]
    unsigned* pairs  = (unsigned*)d_ws;
    int*      esrc   = (int*)(pairs + (size_t)nblk * EPB);
    int*      offs_g = esrc + (size_t)nbins * CAP;
    unsigned* nhraw  = (unsigned*)(offs_g + (size_t)nblk * (NB + 1));
    float*    norms  = (float*)(nhraw + (size_t)N * 32);
    int*      rowbeg = (int*)(norms + N);
    int*      rowend = rowbeg + N;

    int BI = (N * 16 + 1023) / 1024;        // nh blocks
    scatter_kernel<<<nblk, 1024, 0, stream>>>(src, dst, offs_g, pairs, E);
    csr_nh_kernel<<<nbins + BI, 1024, 0, stream>>>(
        pairs, offs_g, rowbeg, rowend, esrc,
        (const float4*)feat, norms, (uint2*)nhraw, N, nbins, nblk);
    gather_kernel<<<(N + 31) / 32, 256, 0, stream>>>(
        (const uint4*)nhraw, norms, beta, rowbeg, rowend, esrc,
        (float4*)d_out, N);
}

// Round 16
// 136.038 us; speedup vs baseline: 1.0851x; 1.0851x over previous
//
#include <hip/hip_runtime.h>
#include <hip/hip_fp16.h>

#define D 64
#define EPS 1e-12f
#define NPB 512         // nodes per dst-bin
#define NPB_SHIFT 9
#define NB 256          // bin table size (nbins = 196 <= 256)
#define CAP 8192        // per-bin esrc region; bin mean 6144, sd 78 -> 26-sigma
#define CAP_SHIFT 13
#define EPB 4096        // edges per scatter block (chunk written contiguously)
#define FRAG_MAX 512    // max scatter blocks (E <= 2.1M); E=1.2M -> 293
#define SRC_BITS 17     // N = 100000 < 2^17

typedef _Float16 hv2 __attribute__((ext_vector_type(2)));

__device__ inline unsigned bc_u(__half2 h) { return __builtin_bit_cast(unsigned, h); }
__device__ inline __half2  bc_h(unsigned u) { return __builtin_bit_cast(__half2, u); }

__device__ inline float fdot2f(unsigned a, unsigned b, float c) {
#if defined(__has_builtin) && __has_builtin(__builtin_amdgcn_fdot2)
    return __builtin_amdgcn_fdot2(__builtin_bit_cast(hv2, a),
                                  __builtin_bit_cast(hv2, b), c, false);
#else
    __half2 ah = bc_h(a), bh = bc_h(b);
    return c + __low2float(ah) * __low2float(bh)
             + __high2float(ah) * __high2float(bh);
#endif
}

// ---- k1: LDS counting-sort by bin; sorted chunk written CONTIGUOUSLY at
//      pairs[blk*EPB] (private, coalesced); per-bin offsets -> offs_g[blk][.].
//      No global atomics, no memset needed. ----
__global__ __launch_bounds__(1024) void scatter_kernel(
        const int* __restrict__ src,
        const int* __restrict__ dst,
        int* __restrict__ offs_g,         // [nblk][NB+1]
        unsigned* __restrict__ pairs, int E) {
    __shared__ int hist[NB], offs[NB + 1], cursor[NB];
    __shared__ int wsum[4];
    __shared__ int dstbuf[EPB];            // 16 KB
    __shared__ unsigned buf[EPB];          // 16 KB

    int tid  = threadIdx.x;
    int base = blockIdx.x * EPB;
    int cnt  = min(EPB, E - base);

    if (tid < NB) hist[tid] = 0;
    __syncthreads();
    for (int i = tid; i < cnt; i += 1024) {
        int dd = dst[base + i];
        dstbuf[i] = dd;
        atomicAdd(&hist[dd >> NPB_SHIFT], 1);
    }
    __syncthreads();
    // exclusive scan of hist[0..NB): 4 waves, shfl scan + wave sums
    int lane = tid & 63, w = tid >> 6;
    int v = 0, x = 0;
    if (tid < NB) { v = hist[tid]; x = v; }
    #pragma unroll
    for (int off = 1; off < 64; off <<= 1) {
        int t = __shfl_up(x, off, 64);
        if (lane >= off) x += t;
    }
    if (tid < NB && lane == 63) wsum[w] = x;
    __syncthreads();
    if (tid < NB) {
        int add = 0;
        #pragma unroll
        for (int ww = 0; ww < 4; ww++) add += (ww < w) ? wsum[ww] : 0;
        int excl = x + add - v;
        offs[tid] = excl; cursor[tid] = excl;
    }
    if (tid == 0) offs[NB] = cnt;
    __syncthreads();
    // sort into LDS (record: local_dst<<17 | src)
    for (int i = tid; i < cnt; i += 1024) {
        int s = src[base + i], dd = dstbuf[i];
        int b = dd >> NPB_SHIFT;
        int l = atomicAdd(&cursor[b], 1);
        buf[l] = ((unsigned)(dd & (NPB - 1)) << SRC_BITS) | (unsigned)s;
    }
    __syncthreads();
    // contiguous coalesced dump of the sorted chunk
    for (int i = tid; i < cnt; i += 1024)
        pairs[base + i] = buf[i];
    // publish per-bin offsets (entire offs_g row written -> poison-safe)
    for (int i = tid; i <= NB; i += 1024)
        offs_g[blockIdx.x * (NB + 1) + i] = offs[i];
}

// ---- k2 (fused, disjoint block ranges):
//      blocks [0,nbins): csr — gather bin fragments from all chunks into LDS,
//                        then hist+scan+rank scatter -> esrc, rowbeg/rowend
//      blocks [nbins,..): nh — norms + f16 normalized rows ----
__global__ __launch_bounds__(1024) void csr_nh_kernel(
        const unsigned* __restrict__ pairs,
        const int* __restrict__ offs_g,
        int* __restrict__ rowbeg,
        int* __restrict__ rowend,
        int* __restrict__ esrc,
        const float4* __restrict__ feat4,
        float* __restrict__ norms,
        uint2* __restrict__ nh2,
        int N, int nbins, int nblk) {
    __shared__ unsigned buf[CAP];                       // 32 KB
    __shared__ int fragsrc[FRAG_MAX], fraglen[FRAG_MAX], fragdst[FRAG_MAX];
    __shared__ int hist[NPB], offsL[NPB];
    __shared__ int wsum[8];
    __shared__ int totcnt;

    if ((int)blockIdx.x >= nbins) {
        // ---------- nh / norms (f16) ----------
        int gid = (blockIdx.x - nbins) * 1024 + threadIdx.x;
        int row = gid >> 4;
        int lg  = gid & 15;
        if (row >= N) return;
        float4 v = feat4[row * 16 + lg];
        float ss = v.x * v.x + v.y * v.y + v.z * v.z + v.w * v.w;
        #pragma unroll
        for (int off = 1; off < 16; off <<= 1) ss += __shfl_xor(ss, off, 64);
        float nrm = fmaxf(sqrtf(ss), EPS);
        float inv = 1.0f / nrm;
        if (lg == 0) norms[row] = nrm;
        uint2 p;
        p.x = bc_u(__floats2half2_rn(v.x * inv, v.y * inv));
        p.y = bc_u(__floats2half2_rn(v.z * inv, v.w * inv));
        nh2[row * 16 + lg] = p;
        return;
    }

    // ---------- csr ----------
    int b    = blockIdx.x;
    int tid  = threadIdx.x;
    int lane = tid & 63, w = tid >> 6;
    int base = b << CAP_SHIFT;         // esrc region for this bin
    int node0 = b << NPB_SHIFT;

    // fragment lengths for bin b across all scatter chunks
    for (int f = tid; f < nblk; f += 1024) {
        int o0 = offs_g[f * (NB + 1) + b];
        int o1 = offs_g[f * (NB + 1) + b + 1];
        fragsrc[f] = o0;
        fraglen[f] = o1 - o0;
    }
    __syncthreads();
    // wave 0: carry-scan of fragment lengths -> fragdst
    if (tid < 64) {
        int carry = 0;
        for (int c = 0; c < nblk; c += 64) {
            int idx = c + tid;
            int ld = (idx < nblk) ? fraglen[idx] : 0;
            int x = ld;
            #pragma unroll
            for (int off = 1; off < 64; off <<= 1) {
                int t = __shfl_up(x, off, 64);
                if (tid >= off) x += t;
            }
            if (idx < nblk) fragdst[idx] = carry + x - ld;
            carry += __shfl(x, 63, 64);
        }
        if (tid == 0) totcnt = carry;
    }
    if (tid < NPB) hist[tid] = 0;
    __syncthreads();
    // gather-copy fragments into contiguous LDS buf (16 waves round-robin)
    for (int f = w; f < nblk; f += 16) {
        int len = fraglen[f];
        int sb = f * EPB + fragsrc[f];
        int db = fragdst[f];
        for (int j = lane; j < len; j += 64)
            buf[db + j] = pairs[sb + j];
    }
    __syncthreads();
    int cnt = totcnt;
    // rank edges per node (register-staged, 8 per thread)
    unsigned rec[8];
    int      meta[8];     // (local_node<<16) | rank
    #pragma unroll
    for (int k = 0; k < 8; k++) {
        int i = tid + (k << 10);
        if (i < cnt) {
            unsigned p = buf[i];
            int ln  = (int)(p >> SRC_BITS);
            rec[k]  = p & ((1u << SRC_BITS) - 1);
            meta[k] = (ln << 16) | atomicAdd(&hist[ln], 1);
        } else meta[k] = -1;
    }
    __syncthreads();
    // exclusive scan of hist[0..NPB): 8 waves, shfl scan + wave sums
    int v = 0, x = 0;
    if (tid < NPB) { v = hist[tid]; x = v; }
    #pragma unroll
    for (int off = 1; off < 64; off <<= 1) {
        int t = __shfl_up(x, off, 64);
        if (lane >= off) x += t;
    }
    if (tid < NPB && lane == 63) wsum[w] = x;
    __syncthreads();
    if (tid < NPB) {
        int add = 0;
        #pragma unroll
        for (int ww = 0; ww < 8; ww++) add += (ww < w) ? wsum[ww] : 0;
        int excl = x + add - v;
        offsL[tid] = excl;
        int node = node0 + tid;
        if (node < N) { rowbeg[node] = base + excl; rowend[node] = base + excl + v; }
    }
    __syncthreads();
    #pragma unroll
    for (int k = 0; k < 8; k++)
        if (meta[k] >= 0)
            esrc[base + offsL[meta[k] >> 16] + (meta[k] & 0xffff)] = (int)rec[k];
}

// ---- k3: gather — one node per 8-lane group, 4-edge unroll (unchanged) ----
__global__ __launch_bounds__(256) void gather_kernel(const uint4* __restrict__ nh4,
                                                     const float* __restrict__ norms,
                                                     const float* __restrict__ beta_p,
                                                     const int* __restrict__ rowbeg,
                                                     const int* __restrict__ rowend,
                                                     const int* __restrict__ esrc,
                                                     float4* __restrict__ out4, int N) {
    int t    = blockIdx.x * 256 + threadIdx.x;
    int lane = threadIdx.x & 63;
    int g    = lane >> 3;
    int lg   = lane & 7;
    int d    = (t >> 6) * 8 + g;
    if (d >= N) return;

    int j   = rowbeg[d];
    int end = rowend[d];
    float beta = beta_p[0];

    uint4 fdp = nh4[(size_t)d * 8 + lg];

    __half2 acc0 = __float2half2_rn(0.f), acc1 = acc0, acc2 = acc0, acc3 = acc0;
    float ps = 0.f;

    for (; j < end; j += 4) {
        bool v1 = (j + 1 < end), v2 = (j + 2 < end), v3 = (j + 3 < end);
        int s0 = esrc[j];
        int s1 = v1 ? esrc[j + 1] : s0;
        int s2 = v2 ? esrc[j + 2] : s0;
        int s3 = v3 ? esrc[j + 3] : s0;
        uint4 p0 = nh4[(size_t)s0 * 8 + lg];
        uint4 p1 = nh4[(size_t)s1 * 8 + lg];
        uint4 p2 = nh4[(size_t)s2 * 8 + lg];
        uint4 p3 = nh4[(size_t)s3 * 8 + lg];
        float n0 = norms[s0], n1 = norms[s1], n2 = norms[s2], n3 = norms[s3];
        float d0 = fdot2f(p0.x, fdp.x, 0.f), d1 = fdot2f(p1.x, fdp.x, 0.f);
        float d2 = fdot2f(p2.x, fdp.x, 0.f), d3 = fdot2f(p3.x, fdp.x, 0.f);
        d0 = fdot2f(p0.y, fdp.y, d0); d1 = fdot2f(p1.y, fdp.y, d1);
        d2 = fdot2f(p2.y, fdp.y, d2); d3 = fdot2f(p3.y, fdp.y, d3);
        d0 = fdot2f(p0.z, fdp.z, d0); d1 = fdot2f(p1.z, fdp.z, d1);
        d2 = fdot2f(p2.z, fdp.z, d2); d3 = fdot2f(p3.z, fdp.z, d3);
        d0 = fdot2f(p0.w, fdp.w, d0); d1 = fdot2f(p1.w, fdp.w, d1);
        d2 = fdot2f(p2.w, fdp.w, d2); d3 = fdot2f(p3.w, fdp.w, d3);
        #pragma unroll
        for (int off = 1; off < 8; off <<= 1) {
            d0 += __shfl_xor(d0, off, 64);
            d1 += __shfl_xor(d1, off, 64);
            d2 += __shfl_xor(d2, off, 64);
            d3 += __shfl_xor(d3, off, 64);
        }
        float w0 = __expf(beta * d0);
        float w1 = v1 ? __expf(beta * d1) : 0.f;
        float w2 = v2 ? __expf(beta * d2) : 0.f;
        float w3 = v3 ? __expf(beta * d3) : 0.f;
        __half2 q0 = __float2half2_rn(w0 * n0);
        __half2 q1 = __float2half2_rn(w1 * n1);
        __half2 q2 = __float2half2_rn(w2 * n2);
        __half2 q3 = __float2half2_rn(w3 * n3);
        acc0 = __hfma2(q0, bc_h(p0.x), acc0); acc0 = __hfma2(q1, bc_h(p1.x), acc0);
        acc0 = __hfma2(q2, bc_h(p2.x), acc0); acc0 = __hfma2(q3, bc_h(p3.x), acc0);
        acc1 = __hfma2(q0, bc_h(p0.y), acc1); acc1 = __hfma2(q1, bc_h(p1.y), acc1);
        acc1 = __hfma2(q2, bc_h(p2.y), acc1); acc1 = __hfma2(q3, bc_h(p3.y), acc1);
        acc2 = __hfma2(q0, bc_h(p0.z), acc2); acc2 = __hfma2(q1, bc_h(p1.z), acc2);
        acc2 = __hfma2(q2, bc_h(p2.z), acc2); acc2 = __hfma2(q3, bc_h(p3.z), acc2);
        acc3 = __hfma2(q0, bc_h(p0.w), acc3); acc3 = __hfma2(q1, bc_h(p1.w), acc3);
        acc3 = __hfma2(q2, bc_h(p2.w), acc3); acc3 = __hfma2(q3, bc_h(p3.w), acc3);
        ps += w0 + w1 + w2 + w3;
    }

    float r = 1.0f / fmaxf(ps, EPS);
    float4 o0 = {__low2float(acc0) * r, __high2float(acc0) * r,
                 __low2float(acc1) * r, __high2float(acc1) * r};
    float4 o1 = {__low2float(acc2) * r, __high2float(acc2) * r,
                 __low2float(acc3) * r, __high2float(acc3) * r};
    out4[(size_t)d * 16 + lg * 2]     = o0;
    out4[(size_t)d * 16 + lg * 2 + 1] = o1;
}

extern "C" void kernel_launch(void* const* d_in, const int* in_sizes, int n_in,
                              void* d_out, int out_size, void* d_ws, size_t ws_size,
                              hipStream_t stream) {
    const float* feat = (const float*)d_in[0];
    const float* beta = (const float*)d_in[1];
    const int*   src  = (const int*)d_in[2];
    const int*   dst  = (const int*)d_in[3];

    int N = in_sizes[0] / D;
    int E = in_sizes[2];
    int nbins = (N + NPB - 1) / NPB;   // 196 (must be <= NB)
    int nblk  = (E + EPB - 1) / EPB;   // 293 (must be <= FRAG_MAX)

    // ws layout — nh table FIRST to keep its 128B rows allocation-aligned
    // (R15 put odd-sized offs_g before it: 20B misalignment -> 1.8x gather fetch).
    // nh[N*64] f16 | pairs[nblk*EPB] u32 | esrc[nbins*CAP] | norms[N] |
    // rowbeg[N] | rowend[N] | offs_g[nblk*(NB+1)]
    unsigned* nhraw  = (unsigned*)d_ws;                  // N*32 uints (12.8 MB)
    unsigned* pairs  = nhraw + (size_t)N * 32;
    int*      esrc   = (int*)(pairs + (size_t)nblk * EPB);
    float*    norms  = (float*)(esrc + (size_t)nbins * CAP);
    int*      rowbeg = (int*)(norms + N);
    int*      rowend = rowbeg + N;
    int*      offs_g = rowend + N;

    int BI = (N * 16 + 1023) / 1024;        // nh blocks
    scatter_kernel<<<nblk, 1024, 0, stream>>>(src, dst, offs_g, pairs, E);
    csr_nh_kernel<<<nbins + BI, 1024, 0, stream>>>(
        pairs, offs_g, rowbeg, rowend, esrc,
        (const float4*)feat, norms, (uint2*)nhraw, N, nbins, nblk);
    gather_kernel<<<(N + 31) / 32, 256, 0, stream>>>(
        (const uint4*)nhraw, norms, beta, rowbeg, rowend, esrc,
        (float4*)d_out, N);
}